// Round 3
// baseline (911.204 us; speedup 1.0000x reference)
//
#include <hip/hip_runtime.h>
#include <stdint.h>

#define D_MODEL 1024
#define D_FF    4096
#define NE      8
#define T_TOK   4096
#define R_TOT   8192   // T_TOK * TOP_K, always exact (top-2 of 8 distinct)

typedef float f32x4 __attribute__((ext_vector_type(4)));
typedef __bf16 bf16x8 __attribute__((ext_vector_type(8)));
typedef unsigned short ushort_t;

__device__ __forceinline__ ushort_t f2bf(float f) {
    unsigned int u = __float_as_uint(f);
    u += 0x7FFFu + ((u >> 16) & 1u);   // round-to-nearest-even
    return (ushort_t)(u >> 16);
}

// async global->LDS, 16B per lane. Pass a WAVE-UNIFORM lds base; HW adds lane*16.
__device__ __forceinline__ void async16(const void* g, const void* l) {
    __builtin_amdgcn_global_load_lds(
        (const __attribute__((address_space(1))) unsigned int*)(uintptr_t)g,
        (__attribute__((address_space(3))) unsigned int*)(uintptr_t)l,
        16, 0, 0);
}

// ---------------- gate: one wave per token ----------------
__global__ __launch_bounds__(256) void k_gate(
    const float* __restrict__ x, const float* __restrict__ Wg, const float* __restrict__ bg,
    int* __restrict__ topi, float* __restrict__ topw, int* __restrict__ counts)
{
    int wave = threadIdx.x >> 6, lane = threadIdx.x & 63;
    int t = blockIdx.x * 4 + wave;
    const float* xr = x + (size_t)t * D_MODEL;
    float acc[NE];
#pragma unroll
    for (int e = 0; e < NE; ++e) acc[e] = 0.f;
#pragma unroll
    for (int i = 0; i < D_MODEL / 64; ++i) {
        int k = i * 64 + lane;
        float xv = xr[k];
        const float4* wgp = (const float4*)(Wg + (size_t)k * NE);
        float4 w0 = wgp[0], w1 = wgp[1];
        acc[0] += xv * w0.x; acc[1] += xv * w0.y; acc[2] += xv * w0.z; acc[3] += xv * w0.w;
        acc[4] += xv * w1.x; acc[5] += xv * w1.y; acc[6] += xv * w1.z; acc[7] += xv * w1.w;
    }
#pragma unroll
    for (int off = 32; off >= 1; off >>= 1)
#pragma unroll
        for (int e = 0; e < NE; ++e) acc[e] += __shfl_down(acc[e], off, 64);
    if (lane == 0) {
        float l[NE], m = -1e30f;
#pragma unroll
        for (int e = 0; e < NE; ++e) { l[e] = acc[e] + bg[e]; m = fmaxf(m, l[e]); }
        float p[NE], Z = 0.f;
#pragma unroll
        for (int e = 0; e < NE; ++e) { p[e] = __expf(l[e] - m); Z += p[e]; }
        float invZ = 1.f / Z;
        int i0 = 0; float v0 = -1.f;
#pragma unroll
        for (int e = 0; e < NE; ++e) { p[e] *= invZ; if (p[e] > v0) { v0 = p[e]; i0 = e; } }
        int i1 = 0; float v1 = -1.f;
#pragma unroll
        for (int e = 0; e < NE; ++e) { if (e != i0 && p[e] > v1) { v1 = p[e]; i1 = e; } }
        float denom = 1.f / (v0 + v1 + 1e-6f);
        topi[t * 2 + 0] = i0; topi[t * 2 + 1] = i1;
        topw[t * 2 + 0] = v0 * denom; topw[t * 2 + 1] = v1 * denom;
        atomicAdd(&counts[i0], 1); atomicAdd(&counts[i1], 1);
    }
}

// ---------------- tiny scan ----------------
__global__ void k_scan(const int* __restrict__ counts, int* __restrict__ offsets,
                       int* __restrict__ cursors)
{
    if (threadIdx.x == 0) {
        int acc = 0;
        for (int e = 0; e < NE; ++e) { offsets[e] = acc; cursors[e] = acc; acc += counts[e]; }
    }
}

// ---------------- scatter tokens into expert buckets ----------------
// Also writes the bucket position back into topi (repurposed as pos map for k_combine).
__global__ __launch_bounds__(256) void k_scatter(
    const int* __restrict__ topi_in, const float* __restrict__ topw,
    int* __restrict__ cursors, int* __restrict__ btok, float* __restrict__ bw)
{
    int t = blockIdx.x * 256 + threadIdx.x;
    int* topi = (int*)topi_in;
#pragma unroll
    for (int k = 0; k < 2; ++k) {
        int e = topi[t * 2 + k];
        int p = atomicAdd(&cursors[e], 1);
        btok[p] = t;
        bw[p] = topw[t * 2 + k];
        topi[t * 2 + k] = p;     // pos map: token -> bucket row
    }
}

// ---------------- gather x rows (bucket order) + fp32->bf16 ----------------
__global__ __launch_bounds__(256) void k_gather(
    const float* __restrict__ x, const int* __restrict__ btok, ushort_t* __restrict__ Xg)
{
    int i = blockIdx.x;
    int t = btok[i];
    float4 v = ((const float4*)(x + (size_t)t * D_MODEL))[threadIdx.x];
    ushort4 o;
    o.x = f2bf(v.x); o.y = f2bf(v.y); o.z = f2bf(v.z); o.w = f2bf(v.w);
    ((ushort4*)(Xg + (size_t)i * D_MODEL))[threadIdx.x] = o;
}

// ---------------- weight transpose+convert: W[e][K][N] fp32 -> Wt[e][N][K] bf16 ----------------
// pad 76: row stride 152 B. store-phase banks: lanes L hit ((4L+i)*38)%32 -> 8 distinct
// positions (2-way, free); 72 gave 2 positions (8-way conflict). 152 % 8 == 0 keeps
// ushort4 LDS reads aligned.
__global__ __launch_bounds__(256) void k_transpose(
    const float* __restrict__ W, ushort_t* __restrict__ Wt, int K, int N)
{
    __shared__ ushort_t tile[64 * 76];
    int e = blockIdx.z;
    const float* We = W + (size_t)e * K * N;
    ushort_t* Wte = Wt + (size_t)e * K * N;
    int nb = blockIdx.x * 64, kb = blockIdx.y * 64;
    int tn4 = (threadIdx.x & 15) * 4;
    int tk = threadIdx.x >> 4;
#pragma unroll
    for (int r = 0; r < 4; ++r) {
        int k = r * 16 + tk;
        float4 v = *(const float4*)(We + (size_t)(kb + k) * N + nb + tn4);
        tile[(tn4 + 0) * 76 + k] = f2bf(v.x);
        tile[(tn4 + 1) * 76 + k] = f2bf(v.y);
        tile[(tn4 + 2) * 76 + k] = f2bf(v.z);
        tile[(tn4 + 3) * 76 + k] = f2bf(v.w);
    }
    __syncthreads();
#pragma unroll
    for (int c = 0; c < 4; ++c) {
        int chunk = c * 256 + threadIdx.x;
        int n = chunk >> 4, kc = (chunk & 15) * 4;
        ushort4 o = *(const ushort4*)&tile[n * 76 + kc];
        *(ushort4*)(Wte + (size_t)(nb + n) * K + kb + kc) = o;
    }
}

// =====================================================================
// Grouped GEMMs. R3 structure: 4-wave blocks (256 thr), 128x128 tile,
// BK=32, per-wave 64x64, double-buffered LDS with counted vmcnt.
// KEY CHANGE vs R1/R2: 48 KB LDS + <=256 VGPR -> TWO independent blocks
// per CU with desynchronized barriers (m114 cross-block overlap). R0-R2
// all pinned at ~575 TF with 1 barrier-locked block/CU regardless of
// intra-block schedule.
//
// LDS tile: 128 rows x 32 elems (64 B row = 4 chunks of 16 B). Chunk c of
// row r stored at slot c ^ ((r>>1)&3): spreads the 16-lane column-read
// across all 8 (row-parity, chunk) bank groups -> 2-way = free. Swizzle
// applied on the GLOBAL source address of global_load_lds; undone on the
// ds_read side.
// =====================================================================

// ---------------- grouped GEMM1: H = silu(Xg@W1 + b1) * (Xg@W3 + b3) ----------------
__global__ __launch_bounds__(256, 2) void k_gemm1(
    const ushort_t* __restrict__ Xg, const ushort_t* __restrict__ W1t,
    const ushort_t* __restrict__ W3t,
    const float* __restrict__ b1, const float* __restrict__ b3,
    const int* __restrict__ counts, const int* __restrict__ offsets,
    ushort_t* __restrict__ H)
{
    __shared__ __align__(16) ushort_t sA [2][128 * 32];   // 16 KB
    __shared__ __align__(16) ushort_t sB1[2][128 * 32];   // 16 KB
    __shared__ __align__(16) ushort_t sB3[2][128 * 32];   // 16 KB

    int bx = blockIdx.x;
    int lx = (bx & 7) * 9 + (bx >> 3);     // bijective: 72 = 8 XCD * 9

    int tm = lx, e = 0, cnt = 0;
    for (; e < NE; ++e) {
        cnt = counts[e];
        int nt = (cnt + 127) >> 7;
        if (tm < nt) break;
        tm -= nt;
    }
    if (e >= NE) return;
    int row0 = offsets[e] + tm * 128;
    int rows_left = cnt - tm * 128;

    int tile_n = blockIdx.y * 128;
    int tid = threadIdx.x, wave = tid >> 6, lane = tid & 63;
    int wm = (wave >> 1) * 64, wn = (wave & 1) * 64;   // 2M x 2N wave grid
    int col = lane & 15, quad = lane >> 4;

    const ushort_t* W1e = W1t + (size_t)e * D_FF * D_MODEL;
    const ushort_t* W3e = W3t + (size_t)e * D_FF * D_MODEL;

    // staging: 24 async16/block (A 8, B1 8, B3 8) -> 6 per wave (2 each)
    const ushort_t* gA[2]; const ushort_t* gB1[2]; const ushort_t* gB3[2];
    unsigned ldsOff[2];
#pragma unroll
    for (int s = 0; s < 2; ++s) {
        int u = wave * 2 + s;                 // instr index 0..7 within each tile
        int q = u * 64 + lane;                // 16B-chunk index in 128x32 tile
        int r = q >> 2;
        int cg = ((q & 3) ^ ((r >> 1) & 3)) * 8;
        gA[s]  = Xg  + (size_t)(row0 + r) * D_MODEL + cg;
        gB1[s] = W1e + (size_t)(tile_n + r) * D_MODEL + cg;
        gB3[s] = W3e + (size_t)(tile_n + r) * D_MODEL + cg;
        ldsOff[s] = (unsigned)u * 512;        // elements (1 KB per instr)
    }

    // frag lds offsets (elements): row*32 + (quad ^ g(row))*8
    unsigned fA[4], fB[4];
#pragma unroll
    for (int i = 0; i < 4; ++i) {
        int ra = wm + i * 16 + col;
        int rb = wn + i * 16 + col;
        fA[i] = (unsigned)ra * 32 + ((quad ^ ((ra >> 1) & 3)) * 8);
        fB[i] = (unsigned)rb * 32 + ((quad ^ ((rb >> 1) & 3)) * 8);
    }

    f32x4 acc1[4][4], acc3[4][4];
#pragma unroll
    for (int i = 0; i < 4; ++i)
#pragma unroll
        for (int j = 0; j < 4; ++j) {
            acc1[i][j] = (f32x4){0.f, 0.f, 0.f, 0.f};
            acc3[i][j] = (f32x4){0.f, 0.f, 0.f, 0.f};
        }

#define STAGE1(p, k0)                                                            \
    do {                                                                         \
        _Pragma("unroll")                                                        \
        for (int s_ = 0; s_ < 2; ++s_) {                                         \
            async16(gA[s_]  + (k0), &sA [p][ldsOff[s_]]);                        \
            async16(gB1[s_] + (k0), &sB1[p][ldsOff[s_]]);                        \
            async16(gB3[s_] + (k0), &sB3[p][ldsOff[s_]]);                        \
        }                                                                        \
    } while (0)

    STAGE1(0, 0);
    for (int t = 0; t < D_MODEL / 32; ++t) {
        int p = t & 1;
        if (t < D_MODEL / 32 - 1) {
            STAGE1(p ^ 1, (t + 1) * 32);
            asm volatile("s_waitcnt vmcnt(6)" ::: "memory");   // tile t landed; t+1 in flight
        } else {
            asm volatile("s_waitcnt vmcnt(0)" ::: "memory");
        }
        __builtin_amdgcn_s_barrier();
        asm volatile("" ::: "memory");

        bf16x8 a[4], u[4];
#pragma unroll
        for (int i = 0; i < 4; ++i) a[i] = *(const bf16x8*)(&sA[p][fA[i]]);
#pragma unroll
        for (int j = 0; j < 4; ++j) u[j] = *(const bf16x8*)(&sB1[p][fB[j]]);
        __builtin_amdgcn_s_setprio(1);
#pragma unroll
        for (int i = 0; i < 4; ++i)
#pragma unroll
            for (int j = 0; j < 4; ++j)
                acc1[i][j] = __builtin_amdgcn_mfma_f32_16x16x32_bf16(a[i], u[j], acc1[i][j], 0, 0, 0);
        __builtin_amdgcn_s_setprio(0);
#pragma unroll
        for (int j = 0; j < 4; ++j) u[j] = *(const bf16x8*)(&sB3[p][fB[j]]);
        __builtin_amdgcn_s_setprio(1);
#pragma unroll
        for (int i = 0; i < 4; ++i)
#pragma unroll
            for (int j = 0; j < 4; ++j)
                acc3[i][j] = __builtin_amdgcn_mfma_f32_16x16x32_bf16(a[i], u[j], acc3[i][j], 0, 0, 0);
        __builtin_amdgcn_s_setprio(0);
        asm volatile("" ::: "memory");
        __builtin_amdgcn_s_barrier();
        asm volatile("" ::: "memory");
    }
#undef STAGE1

#pragma unroll
    for (int j = 0; j < 4; ++j) {
        int n = tile_n + wn + j * 16 + col;
        float bias1 = b1[e * D_FF + n];
        float bias3 = b3[e * D_FF + n];
#pragma unroll
        for (int i = 0; i < 4; ++i) {
            int rbase = wm + i * 16 + quad * 4;
#pragma unroll
            for (int r = 0; r < 4; ++r) {
                int row = rbase + r;
                if (row < rows_left) {
                    float h1 = acc1[i][j][r] + bias1;
                    float h3 = acc3[i][j][r] + bias3;
                    float s = h1 / (1.f + __expf(-h1));   // silu
                    H[(size_t)(row0 + row) * D_FF + n] = f2bf(s * h3);
                }
            }
        }
    }
}

// ---------------- grouped GEMM2: Y[bucket_row] = H @ W2 + b2 (plain stores) ----------------
__global__ __launch_bounds__(256, 4) void k_gemm2(
    const ushort_t* __restrict__ H, const ushort_t* __restrict__ W2t,
    const float* __restrict__ b2,
    const int* __restrict__ counts, const int* __restrict__ offsets,
    float* __restrict__ Y)
{
    __shared__ __align__(16) ushort_t sA[2][128 * 32];   // 16 KB
    __shared__ __align__(16) ushort_t sB[2][128 * 32];   // 16 KB

    int bx = blockIdx.x;
    int lx = (bx & 7) * 9 + (bx >> 3);

    int tm = lx, e = 0, cnt = 0;
    for (; e < NE; ++e) {
        cnt = counts[e];
        int nt = (cnt + 127) >> 7;
        if (tm < nt) break;
        tm -= nt;
    }
    if (e >= NE) return;
    int row0 = offsets[e] + tm * 128;
    int rows_left = cnt - tm * 128;

    int tile_n = blockIdx.y * 128;
    int tid = threadIdx.x, wave = tid >> 6, lane = tid & 63;
    int wm = (wave >> 1) * 64, wn = (wave & 1) * 64;
    int col = lane & 15, quad = lane >> 4;

    const ushort_t* W2e = W2t + (size_t)e * D_MODEL * D_FF;

    const ushort_t* gA[2]; const ushort_t* gB[2];
    unsigned ldsOff[2];
#pragma unroll
    for (int s = 0; s < 2; ++s) {
        int u = wave * 2 + s;
        int q = u * 64 + lane;
        int r = q >> 2;
        int cg = ((q & 3) ^ ((r >> 1) & 3)) * 8;
        gA[s] = H   + (size_t)(row0 + r) * D_FF + cg;
        gB[s] = W2e + (size_t)(tile_n + r) * D_FF + cg;
        ldsOff[s] = (unsigned)u * 512;
    }

    unsigned fA[4], fB[4];
#pragma unroll
    for (int i = 0; i < 4; ++i) {
        int ra = wm + i * 16 + col;
        int rb = wn + i * 16 + col;
        fA[i] = (unsigned)ra * 32 + ((quad ^ ((ra >> 1) & 3)) * 8);
        fB[i] = (unsigned)rb * 32 + ((quad ^ ((rb >> 1) & 3)) * 8);
    }

    f32x4 acc[4][4];
#pragma unroll
    for (int i = 0; i < 4; ++i)
#pragma unroll
        for (int j = 0; j < 4; ++j) acc[i][j] = (f32x4){0.f, 0.f, 0.f, 0.f};

#define STAGE2(p, k0)                                                            \
    do {                                                                         \
        _Pragma("unroll")                                                        \
        for (int s_ = 0; s_ < 2; ++s_) {                                         \
            async16(gA[s_] + (k0), &sA[p][ldsOff[s_]]);                          \
            async16(gB[s_] + (k0), &sB[p][ldsOff[s_]]);                          \
        }                                                                        \
    } while (0)

    STAGE2(0, 0);
    for (int t = 0; t < D_FF / 32; ++t) {
        int p = t & 1;
        if (t < D_FF / 32 - 1) {
            STAGE2(p ^ 1, (t + 1) * 32);
            asm volatile("s_waitcnt vmcnt(4)" ::: "memory");
        } else {
            asm volatile("s_waitcnt vmcnt(0)" ::: "memory");
        }
        __builtin_amdgcn_s_barrier();
        asm volatile("" ::: "memory");

        bf16x8 a[4], b[4];
#pragma unroll
        for (int i = 0; i < 4; ++i) a[i] = *(const bf16x8*)(&sA[p][fA[i]]);
#pragma unroll
        for (int j = 0; j < 4; ++j) b[j] = *(const bf16x8*)(&sB[p][fB[j]]);
        __builtin_amdgcn_s_setprio(1);
#pragma unroll
        for (int i = 0; i < 4; ++i)
#pragma unroll
            for (int j = 0; j < 4; ++j)
                acc[i][j] = __builtin_amdgcn_mfma_f32_16x16x32_bf16(a[i], b[j], acc[i][j], 0, 0, 0);
        __builtin_amdgcn_s_setprio(0);
        asm volatile("" ::: "memory");
        __builtin_amdgcn_s_barrier();
        asm volatile("" ::: "memory");
    }
#undef STAGE2

    float bias[4];
#pragma unroll
    for (int j = 0; j < 4; ++j) bias[j] = b2[e * D_MODEL + tile_n + wn + j * 16 + col];

#pragma unroll
    for (int i = 0; i < 4; ++i) {
        int rbase = wm + i * 16 + quad * 4;
#pragma unroll
        for (int r = 0; r < 4; ++r) {
            int row = rbase + r;
            if (row < rows_left) {
                float* yrow = Y + (size_t)(row0 + row) * D_MODEL + tile_n + wn + col;
#pragma unroll
                for (int j = 0; j < 4; ++j)
                    yrow[j * 16] = acc[i][j][r] + bias[j];
            }
        }
    }
}

// ---------------- combine: out[t] = w0*Y[p0] + w1*Y[p1] ----------------
__global__ __launch_bounds__(256) void k_combine(
    const float* __restrict__ Y, const int* __restrict__ pos,
    const float* __restrict__ topw, float* __restrict__ out)
{
    int t = blockIdx.x, c = threadIdx.x;
    int p0 = pos[t * 2 + 0], p1 = pos[t * 2 + 1];
    float w0 = topw[t * 2 + 0], w1 = topw[t * 2 + 1];
    float4 y0 = ((const float4*)(Y + (size_t)p0 * D_MODEL))[c];
    float4 y1 = ((const float4*)(Y + (size_t)p1 * D_MODEL))[c];
    float4 o;
    o.x = w0 * y0.x + w1 * y1.x;
    o.y = w0 * y0.y + w1 * y1.y;
    o.z = w0 * y0.z + w1 * y1.z;
    o.w = w0 * y0.w + w1 * y1.w;
    ((float4*)(out + (size_t)t * D_MODEL))[c] = o;
}

extern "C" void kernel_launch(void* const* d_in, const int* in_sizes, int n_in,
                              void* d_out, int out_size, void* d_ws, size_t ws_size,
                              hipStream_t stream)
{
    const float* x  = (const float*)d_in[0];
    const float* Wg = (const float*)d_in[1];
    const float* bg = (const float*)d_in[2];
    const float* W1 = (const float*)d_in[3];
    const float* b1 = (const float*)d_in[4];
    const float* W3 = (const float*)d_in[5];
    const float* b3 = (const float*)d_in[6];
    const float* W2 = (const float*)d_in[7];
    const float* b2 = (const float*)d_in[8];
    float* out = (float*)d_out;

    char* ws = (char*)d_ws;
    int*   counts  = (int*)(ws + 0);
    int*   cursors = (int*)(ws + 32);
    int*   offsets = (int*)(ws + 64);
    int*   topi    = (int*)(ws + 256);
    float* topw    = (float*)(ws + 256 + 32768);
    int*   btok    = (int*)(ws + 256 + 65536);
    float* bw      = (float*)(ws + 256 + 98304);
    char* p = ws + 131328;
    ushort_t* Xg  = (ushort_t*)p;  p += (size_t)R_TOT * D_MODEL * 2;      // 16.78 MB
    ushort_t* Hb  = (ushort_t*)p;  p += (size_t)R_TOT * D_FF * 2;         // 67.1 MB
    ushort_t* W1t = (ushort_t*)p;  p += (size_t)NE * D_FF * D_MODEL * 2;  // 67.1 MB
    ushort_t* W3t = (ushort_t*)p;  p += (size_t)NE * D_FF * D_MODEL * 2;  // 67.1 MB
    ushort_t* W2t = (ushort_t*)p;                                          // 67.1 MB
    // Y overlays W1t (dead after k_gemm1): 8192*1024*4 = 33.5 MB <= 67.1 MB
    float* Y = (float*)W1t;

    hipMemsetAsync(ws, 0, 64, stream);                       // counts + cursors

    k_gate<<<dim3(T_TOK / 4), dim3(256), 0, stream>>>(x, Wg, bg, topi, topw, counts);
    k_scan<<<dim3(1), dim3(64), 0, stream>>>(counts, offsets, cursors);
    k_scatter<<<dim3(T_TOK / 256), dim3(256), 0, stream>>>(topi, topw, cursors, btok, bw);
    k_gather<<<dim3(R_TOT), dim3(256), 0, stream>>>(x, btok, Xg);
    k_transpose<<<dim3(D_FF / 64, D_MODEL / 64, NE), dim3(256), 0, stream>>>(W1, W1t, D_MODEL, D_FF);
    k_transpose<<<dim3(D_FF / 64, D_MODEL / 64, NE), dim3(256), 0, stream>>>(W3, W3t, D_MODEL, D_FF);
    k_transpose<<<dim3(D_MODEL / 64, D_FF / 64, NE), dim3(256), 0, stream>>>(W2, W2t, D_FF, D_MODEL);
    // grid.x = 72 = max row-tiles at 128-granularity (<=71) and = 8 XCDs * 9 for the swizzle
    k_gemm1<<<dim3(72, D_FF / 128), dim3(256), 0, stream>>>(Xg, W1t, W3t, b1, b3, counts, offsets, Hb);
    k_gemm2<<<dim3(72, D_MODEL / 128), dim3(256), 0, stream>>>(Hb, W2t, b2, counts, offsets, Y);
    k_combine<<<dim3(T_TOK), dim3(256), 0, stream>>>(Y, topi, topw, out);
}